// Round 1
// baseline (1040.884 us; speedup 1.0000x reference)
//
#include <hip/hip_runtime.h>
#include <stdint.h>

// ---------------------------------------------------------------------------
// VQ-VAE forward on MI355X. Round 5: dec2 rewrite. Old dec2 was latency-bound
// (VALUBusy 28%, HBM 15%, 171 us vs ~30 us VALU floor): 72 strided global
// uint4 loads/px, branchy taps, no staging. New dec2: 32x32 tile/block, LDS
// double-buffered 34x34 halo tile in 8-channel chunks via global_load_lds
// (coalesced), thread = 4x1 output strip (input reuse), zero-page halo,
// uniform scalar weight loads. Stage(c+1) issued before compute(c) so the
// end-of-iter barrier drain hides load latency (T3-minimum 2-phase).
// Rest identical to R4.
// ---------------------------------------------------------------------------

typedef unsigned short bfraw;
typedef __attribute__((ext_vector_type(8))) short s16x8;
typedef __attribute__((ext_vector_type(4))) float f32x4;

__device__ __forceinline__ float bflo(unsigned int u) {
    union { unsigned int i; float f; } v; v.i = u << 16; return v.f;
}
__device__ __forceinline__ float bfhi(unsigned int u) {
    union { unsigned int i; float f; } v; v.i = u & 0xFFFF0000u; return v.f;
}
__device__ __forceinline__ bfraw f2bf(float f) {
    union { float f; unsigned int i; } v; v.f = f;
    unsigned int r = v.i + 0x7FFFu + ((v.i >> 16) & 1u);   // RNE
    return (bfraw)(r >> 16);
}

// async 16B global->LDS. LDS dest: wave-uniform base + lane*16.
__device__ __forceinline__ void gl_lds16(const void* g, void* l) {
    auto gp = reinterpret_cast<const __attribute__((address_space(1))) unsigned int*>(
        reinterpret_cast<uintptr_t>(g));
    auto lp = reinterpret_cast<__attribute__((address_space(3))) unsigned int*>(
        reinterpret_cast<uintptr_t>(l));
    __builtin_amdgcn_global_load_lds(gp, lp, 16, 0, 0);
}

// --- weight transform (fp32, [tap][ci][co]) for dec2
__global__ void wt_kernel(const float* __restrict__ w, float* __restrict__ wt,
                          int Cout, int Cin, int KH, int KW, int transposed) {
    int n = Cout * Cin * KH * KW;
    for (int i = blockIdx.x * blockDim.x + threadIdx.x; i < n; i += gridDim.x * blockDim.x) {
        int co = i % Cout; int t = i / Cout;
        int ci = t % Cin;  int tap = t / Cin;
        int kw = tap % KW; int kh = tap / KW;
        float v = transposed ? w[(((long)ci * Cout + co) * KH + kh) * KW + kw]
                             : w[(((long)co * Cin + ci) * KH + kh) * KW + kw];
        wt[i] = v;
    }
}

// --- weight transform (bf16, [co][tap][ci]) for MFMA convs (B as [n][k]);
//     with KH=KW=1 also converts emb[512][256] to bf16 B layout.
__global__ void wtb_kernel(const float* __restrict__ w, bfraw* __restrict__ wt,
                           int Cout, int Cin, int KH, int KW, int transposed) {
    int n = Cout * Cin * KH * KW;
    int NT = KH * KW;
    for (int i = blockIdx.x * blockDim.x + threadIdx.x; i < n; i += gridDim.x * blockDim.x) {
        int ci = i % Cin; int t = i / Cin;
        int tap = t % NT; int co = t / NT;
        int kh = tap / KW, kw = tap % KW;
        float v = transposed ? w[(((long)ci * Cout + co) * KH + kh) * KW + kw]
                             : w[(((long)co * Cin + ci) * KH + kh) * KW + kw];
        wt[i] = f2bf(v);
    }
}

// --- enc1 weight pack: wb1[co][k64], k=(kh*4+kw)*3+ci (48 real, 16 zero)
__global__ void wb1_kernel(const float* __restrict__ w, bfraw* __restrict__ wt) {
    int i = blockIdx.x * 256 + threadIdx.x;
    if (i >= 4096) return;
    int k = i & 63, co = i >> 6;
    bfraw v = 0;
    if (k < 48) {
        int ci = k % 3, tap = k / 3, kh = tap >> 2, kw = tap & 3;
        v = f2bf(w[(((long)co * 3 + ci) * 4 + kh) * 4 + kw]);
    }
    wt[(long)co * 64 + k] = v;
}

// --- enc1 im2col: x NCHW fp32 -> A0[pos][64] bf16 (48 patch vals + 16 zeros)
__global__ __launch_bounds__(256) void xpack_kernel(const float* __restrict__ x,
                                                    bfraw* __restrict__ a0) {
    int pos = blockIdx.x * 256 + threadIdx.x;        // 262144
    int ow = pos & 127, oh = (pos >> 7) & 127, n = pos >> 14;
    __align__(16) bfraw v[64];
#pragma unroll
    for (int i = 0; i < 64; ++i) v[i] = 0;
#pragma unroll
    for (int kh = 0; kh < 4; ++kh) {
        int ih = 2 * oh - 1 + kh; if ((unsigned)ih >= 256u) continue;
#pragma unroll
        for (int kw = 0; kw < 4; ++kw) {
            int iw = 2 * ow - 1 + kw; if ((unsigned)iw >= 256u) continue;
#pragma unroll
            for (int ci = 0; ci < 3; ++ci)
                v[(kh * 4 + kw) * 3 + ci] =
                    f2bf(x[(((long)n * 3 + ci) * 256 + ih) * 256 + iw]);
        }
    }
    uint4* dst = (uint4*)(a0 + (long)pos * 64);
    const uint4* src = (const uint4*)v;
#pragma unroll
    for (int i = 0; i < 8; ++i) dst[i] = src[i];
}

// --- emb row norms
__global__ void embsq_kernel(const float* __restrict__ emb, float* __restrict__ esq) {
    int k = blockIdx.x, lane = threadIdx.x;
    float s = 0.f;
    for (int d = lane; d < 256; d += 64) { float v = emb[k * 256 + d]; s += v * v; }
    for (int o = 32; o; o >>= 1) s += __shfl_down(s, o, 64);
    if (lane == 0) esq[k] = s;
}

// ---------------------------------------------------------------------------
// MFMA implicit GEMM. C[MxN] = A[MxK]*B[KxN].
// ---------------------------------------------------------------------------
template<int BM, int BN, int WM, int WN, bool TR, bool RELU, bool OUTF32, bool DUALB>
__global__ __launch_bounds__(256) void igemm_kernel(
    const bfraw* __restrict__ in, const bfraw* __restrict__ wt,
    const float* __restrict__ bias, void* __restrict__ outv,
    bfraw* __restrict__ outb, const bfraw* __restrict__ zp,
    int Hin, int Win, int Cin, int sf, int NTW, int Ksteps,
    int lw, int lh, int N, int KW, int pad, int py, int px,
    unsigned long long pack)
{
    constexpr int APASS = BM / 64, BPASS = BN / 64;
    __shared__ __align__(16) bfraw ldsA[BM * 32];
    __shared__ __align__(16) bfraw ldsB[BN * 32];
    const int tid = threadIdx.x, lane = tid & 63, wv = tid >> 6;
    const int wm = wv / WN, wn = wv % WN;
    const int lrow = lane >> 2, lkof = (lane & 3) * 8;
    const int blockM = blockIdx.x, n0 = blockIdx.y * BN;
    const int Wm1 = (1 << lw) - 1, Hm1 = (1 << lh) - 1;

    long baseA[APASS]; int ihb[APASS], iwb[APASS];
#pragma unroll
    for (int p = 0; p < APASS; ++p) {
        int m = p * 64 + wv * 16 + lrow;
        int pos = blockM * BM + m;
        int ow = pos & Wm1; int t = pos >> lw;
        int oh = t & Hm1;   int nb = t >> lh;
        ihb[p] = oh * sf; iwb[p] = ow * sf;
        baseA[p] = ((long)(nb * Hin + ihb[p]) * Win + iwb[p]) * (long)Cin + lkof;
    }
    long baseB[BPASS];
#pragma unroll
    for (int p = 0; p < BPASS; ++p) {
        int nl = p * 64 + wv * 16 + lrow;
        baseB[p] = (long)(n0 + nl) * ((long)NTW * Cin) + lkof;
    }

    f32x4 acc[4][4];
#pragma unroll
    for (int i = 0; i < 4; ++i)
#pragma unroll
        for (int j = 0; j < 4; ++j) acc[i][j] = (f32x4)0.f;

    int ci0 = 0, tslot = 0, dy, dx, wk;
    if (TR) {
        unsigned e = (unsigned)pack & 0xFFFFu;
        dy = (int)((e >> 8) & 3) - 1; dx = (int)((e >> 4) & 3) - 1; wk = (int)(e & 15u);
    } else { dy = -pad; dx = -pad; wk = 0; }

    const int quad = lane >> 4, r16 = lane & 15;

    for (int ks = 0; ks < Ksteps; ++ks) {
        long offA = ((long)(dy * Win + dx)) * Cin + ci0;
        long offB = (long)wk * Cin + ci0;
#pragma unroll
        for (int p = 0; p < APASS; ++p) {
            int ih = ihb[p] + dy, iw = iwb[p] + dx;
            bool ok = ((unsigned)ih < (unsigned)Hin) & ((unsigned)iw < (unsigned)Win);
            const bfraw* g = ok ? (in + baseA[p] + offA) : (zp + lkof);
            gl_lds16(g, &ldsA[(p * 64 + wv * 16) * 32]);
        }
#pragma unroll
        for (int p = 0; p < BPASS; ++p)
            gl_lds16(wt + baseB[p] + offB, &ldsB[(p * 64 + wv * 16) * 32]);
        __syncthreads();
        s16x8 af[4], bf[4];
#pragma unroll
        for (int i = 0; i < 4; ++i)
            af[i] = *(const s16x8*)&ldsA[(wm * 64 + i * 16 + r16) * 32 + quad * 8];
#pragma unroll
        for (int j = 0; j < 4; ++j)
            bf[j] = *(const s16x8*)&ldsB[(wn * 64 + j * 16 + r16) * 32 + quad * 8];
#pragma unroll
        for (int i = 0; i < 4; ++i)
#pragma unroll
            for (int j = 0; j < 4; ++j)
                acc[i][j] = __builtin_amdgcn_mfma_f32_16x16x32_bf16(af[i], bf[j], acc[i][j], 0, 0, 0);
        __syncthreads();
        ci0 += 32;
        if (ci0 == Cin) {
            ci0 = 0; ++tslot;
            if (TR) {
                unsigned e = (unsigned)(pack >> (tslot * 16)) & 0xFFFFu;
                dy = (int)((e >> 8) & 3) - 1; dx = (int)((e >> 4) & 3) - 1; wk = (int)(e & 15u);
            } else { ++wk; ++dx; if (dx == KW - pad) { dx = -pad; ++dy; } }
        }
    }

#pragma unroll
    for (int j = 0; j < 4; ++j) {
        int col = wn * 64 + j * 16 + r16; int ng = n0 + col;
        float bv = bias[ng];
#pragma unroll
        for (int i = 0; i < 4; ++i) {
            int mb = wm * 64 + i * 16 + quad * 4;
#pragma unroll
            for (int r = 0; r < 4; ++r) {
                int pos2 = blockM * BM + mb + r;
                long oaddr;
                if (TR) {
                    int ow2 = pos2 & Wm1; int t = pos2 >> lw;
                    int oh2 = t & Hm1;    int nb = t >> lh;
                    int oh = 2 * oh2 + py, ow = 2 * ow2 + px;
                    oaddr = ((long)(((nb << (lh + 1)) + oh) << (lw + 1)) + ow) * N + ng;
                } else {
                    oaddr = (long)pos2 * N + ng;
                }
                float v = acc[i][j][r] + bv;
                if (RELU) v = fmaxf(v, 0.f);
                if (OUTF32) {
                    ((float*)outv)[oaddr] = v;
                    if (DUALB) outb[oaddr] = f2bf(v);
                } else {
                    ((bfraw*)outv)[oaddr] = f2bf(v);
                }
            }
        }
    }
}

// ---------------------------------------------------------------------------
// dec2: convT k3 s1 p1, 64->3ch, fp32 NCHW out.
// Block = 32x32 output tile (grid 16 n * 64 tiles = 1024 = 4 blocks/CU).
// Thread = 4x1 output strip (col = tid&31, rows = 4*(tid>>5)+[0..3]).
// Input staged in LDS: 34x34 halo tile, 8-channel chunks, double-buffered
// (2 x 18496 B). global_load_lds sources are consecutive pixels (contiguous
// in the [pos][64] bf16 layout) -> fully coalesced; OOB halo -> zero page.
// Weights: uniform addresses -> scalar loads (SMEM pipe, no VALU cost).
// ---------------------------------------------------------------------------
__global__ __launch_bounds__(256) void dec2_kernel(
    const bfraw* __restrict__ in, const float* __restrict__ wt,
    const float* __restrict__ bias, float* __restrict__ out,
    const bfraw* __restrict__ zp) {
    __shared__ __align__(16) bfraw buf[2][1156 * 8];   // 2 x 18,496 B
    const int tid = threadIdx.x;
    const int b = blockIdx.x;
    const int n = b >> 6, t6 = b & 63;
    const int r0 = (t6 >> 3) * 32, c0 = (t6 & 7) * 32;
    const int wv = tid >> 6;
    const int ow_l = tid & 31, rbase = (tid >> 5) * 4;

    // staging sources: seg s = pixel index in 34x34 halo tile (16B = 8ch/px).
    // s = tid + k*256, k=0..3 full, k=4 only tid<132 (1156 segs total).
    const bfraw* gsrc[5];
#pragma unroll
    for (int k = 0; k < 5; ++k) {
        int s = tid + k * 256; if (s >= 1156) s = 0;        // dummy, never issued
        int pr = s / 34, pc = s - pr * 34;
        int ih = r0 - 1 + pr, iw = c0 - 1 + pc;
        bool ok = ((unsigned)ih < 256u) & ((unsigned)iw < 256u);
        gsrc[k] = ok ? in + (((long)(n * 256 + ih)) * 256 + iw) * 64 : zp;
    }

    float acc[4][3];
    {
        float b0 = bias[0], b1 = bias[1], b2 = bias[2];
#pragma unroll
        for (int j = 0; j < 4; ++j) { acc[j][0] = b0; acc[j][1] = b1; acc[j][2] = b2; }
    }

    // prologue: stage chunk 0 into buf[0]
#pragma unroll
    for (int k = 0; k < 4; ++k)
        gl_lds16(gsrc[k], &buf[0][(wv * 64 + k * 256) * 8]);
    if (tid < 132) gl_lds16(gsrc[4], &buf[0][(wv * 64 + 1024) * 8]);
    __syncthreads();

    for (int c = 0; c < 8; ++c) {                  // 8 channel chunks of 8
        const int cur = c & 1;
        if (c < 7) {
            const int nc = c + 1, nb = nc & 1;     // issue next stage BEFORE compute
#pragma unroll
            for (int k = 0; k < 4; ++k)
                gl_lds16(gsrc[k] + nc * 8, &buf[nb][(wv * 64 + k * 256) * 8]);
            if (tid < 132) gl_lds16(gsrc[4] + nc * 8, &buf[nb][(wv * 64 + 1024) * 8]);
        }
        const bfraw* B = buf[cur];
        const float* wc = wt + c * 24;             // [tap][ci][co]: ci block c*8
#pragma unroll
        for (int pr6 = 0; pr6 < 6; ++pr6) {        // 6 input rows feed 4 outputs
            const int prow = rbase + pr6;
#pragma unroll
            for (int pc3 = 0; pc3 < 3; ++pc3) {    // 3 input cols feed 1 out col
                const int pcol = ow_l + pc3;
                uint4 u = *(const uint4*)&B[(prow * 34 + pcol) * 8];
                float v[8];
                v[0] = bflo(u.x); v[1] = bfhi(u.x);
                v[2] = bflo(u.y); v[3] = bfhi(u.y);
                v[4] = bflo(u.z); v[5] = bfhi(u.z);
                v[6] = bflo(u.w); v[7] = bfhi(u.w);
                const int kw = 2 - pc3;
#pragma unroll
                for (int j = 0; j < 4; ++j) {
                    const int kh = j + 2 - pr6;    // compile-time per (pr6,j)
                    if (kh < 0 || kh > 2) continue;
                    const float* w0 = wc + (kh * 3 + kw) * 192;
#pragma unroll
                    for (int cc = 0; cc < 8; ++cc) {
                        float vv = v[cc];
                        acc[j][0] = fmaf(vv, w0[cc * 3 + 0], acc[j][0]);
                        acc[j][1] = fmaf(vv, w0[cc * 3 + 1], acc[j][1]);
                        acc[j][2] = fmaf(vv, w0[cc * 3 + 2], acc[j][2]);
                    }
                }
            }
        }
        __syncthreads();    // drains stage(c+1) after ~2300cy of FMA; guards reuse
    }

    const int ow = c0 + ow_l;
    const long sp = (long)n * 196608;
#pragma unroll
    for (int j = 0; j < 4; ++j) {
        long hw = (long)(r0 + rbase + j) * 256 + ow;
        out[sp + hw] = acc[j][0];
        out[sp + 65536 + hw] = acc[j][1];
        out[sp + 131072 + hw] = acc[j][2];
    }
}

// ---------------------------------------------------------------------------
// VQ via MFMA: S = Zb[128 x 256] x EbT (codes as B rows), dist = ||e||^2 - 2S.
// Two waves share each 64-row group (different code halves): partial argmins
// are merged via LDS before ONE sIdx write + ONE hist atomic per row.
// ---------------------------------------------------------------------------
__global__ __launch_bounds__(256) void vqm_kernel(
    const bfraw* __restrict__ zeb, const bfraw* __restrict__ embB,
    const float* __restrict__ esq, const float* __restrict__ emb,
    float* __restrict__ zq, bfraw* __restrict__ zqb, int* __restrict__ hist)
{
    __shared__ __align__(16) bfraw ldsA[128 * 32];
    __shared__ __align__(16) bfraw ldsB[128 * 32];
    __shared__ float sEsq[512];
    __shared__ float sVal[2][128];
    __shared__ int   sKey[2][128];
    __shared__ int   sIdx[128];
    const int tid = threadIdx.x, lane = tid & 63, wv = tid >> 6;
    const int wm = wv >> 1, wn = wv & 1;
    const int lrow = lane >> 2, lkof = (lane & 3) * 8;
    const int quad = lane >> 4, r16 = lane & 15;
    const int posBase = blockIdx.x * 128;

    for (int i = tid; i < 512; i += 256) sEsq[i] = esq[i];

    const long baseA0 = (long)(posBase + wv * 16 + lrow) * 256 + lkof;
    const long baseA1 = baseA0 + 64 * 256;

    float bestv[16]; int bestk[16];
#pragma unroll
    for (int t = 0; t < 16; ++t) { bestv[t] = 1e30f; bestk[t] = 1 << 30; }

    for (int chunk = 0; chunk < 4; ++chunk) {
        f32x4 acc[4][4];
#pragma unroll
        for (int i = 0; i < 4; ++i)
#pragma unroll
            for (int j = 0; j < 4; ++j) acc[i][j] = (f32x4)0.f;
        const long baseB0 = (long)(chunk * 128 + wv * 16 + lrow) * 256 + lkof;
        const long baseB1 = baseB0 + 64 * 256;
        for (int k = 0; k < 8; ++k) {
            gl_lds16(zeb + baseA0 + k * 32, &ldsA[(wv * 16) * 32]);
            gl_lds16(zeb + baseA1 + k * 32, &ldsA[(64 + wv * 16) * 32]);
            gl_lds16(embB + baseB0 + k * 32, &ldsB[(wv * 16) * 32]);
            gl_lds16(embB + baseB1 + k * 32, &ldsB[(64 + wv * 16) * 32]);
            __syncthreads();
            s16x8 af[4], bf[4];
#pragma unroll
            for (int i = 0; i < 4; ++i)
                af[i] = *(const s16x8*)&ldsA[(wm * 64 + i * 16 + r16) * 32 + quad * 8];
#pragma unroll
            for (int j = 0; j < 4; ++j)
                bf[j] = *(const s16x8*)&ldsB[(wn * 64 + j * 16 + r16) * 32 + quad * 8];
#pragma unroll
            for (int i = 0; i < 4; ++i)
#pragma unroll
                for (int j = 0; j < 4; ++j)
                    acc[i][j] = __builtin_amdgcn_mfma_f32_16x16x32_bf16(af[i], bf[j], acc[i][j], 0, 0, 0);
            __syncthreads();
        }
        // chunk epilogue: dist + argmin. C row = i*16 + quad*4 + r, col = r16.
#pragma unroll
        for (int i = 0; i < 4; ++i) {
#pragma unroll
            for (int r = 0; r < 4; ++r) {
                float v = 1e30f; int kk = 1 << 30;
#pragma unroll
                for (int j = 0; j < 4; ++j) {
                    int code = chunk * 128 + wn * 64 + j * 16 + r16;
                    float d = sEsq[code] - 2.f * acc[i][j][r];
                    if (d < v || (d == v && code < kk)) { v = d; kk = code; }
                }
#pragma unroll
                for (int m = 1; m < 16; m <<= 1) {
                    float ov = __shfl_xor(v, m, 64);
                    int   ok = __shfl_xor(kk, m, 64);
                    if (ov < v || (ov == v && ok < kk)) { v = ov; kk = ok; }
                }
                int s = i * 4 + r;
                if (v < bestv[s] || (v == bestv[s] && kk < bestk[s])) {
                    bestv[s] = v; bestk[s] = kk;
                }
            }
        }
    }
    // publish per-wave partials (each wave covered half the codes for its rows)
    if (r16 == 0) {
#pragma unroll
        for (int i = 0; i < 4; ++i)
#pragma unroll
            for (int r = 0; r < 4; ++r) {
                int localRow = wm * 64 + i * 16 + quad * 4 + r;
                int s = i * 4 + r;
                sVal[wn][localRow] = bestv[s];
                sKey[wn][localRow] = bestk[s];
            }
    }
    __syncthreads();
    // merge halves: one thread per row, single sIdx write + single hist atomic
    if (tid < 128) {
        float v0 = sVal[0][tid]; int k0 = sKey[0][tid];
        float v1 = sVal[1][tid]; int k1 = sKey[1][tid];
        int kk = (v1 < v0 || (v1 == v0 && k1 < k0)) ? k1 : k0;
        sIdx[tid] = kk;
        atomicAdd(&hist[kk], 1);
    }
    __syncthreads();
    const float4* emb4 = (const float4*)emb;
    float4*  zq4  = (float4*)(zq + (long)posBase * 256);
    ushort4* zqb4 = (ushort4*)(zqb + (long)posBase * 256);
    for (int i2 = tid; i2 < 128 * 64; i2 += 256) {
        int p = i2 >> 6, c = i2 & 63;
        float4 vv = emb4[sIdx[p] * 64 + c];
        zq4[i2] = vv;
        ushort4 u; u.x = f2bf(vv.x); u.y = f2bf(vv.y); u.z = f2bf(vv.z); u.w = f2bf(vv.w);
        zqb4[i2] = u;
    }
}

// --- perplexity
__global__ void ppl_kernel(const int* __restrict__ hist, float* __restrict__ outp) {
    __shared__ float red[512];
    int t = threadIdx.x;
    float p = (float)hist[t] * (1.0f / 65536.0f);
    red[t] = p * logf(p + 1e-10f);
    __syncthreads();
    for (int s = 256; s; s >>= 1) { if (t < s) red[t] += red[t + s]; __syncthreads(); }
    if (t == 0) *outp = expf(-red[0]);
}

// host: pack convT parity-class tap table (4 entries x 16 bits)
static unsigned long long packFor(int py, int px) {
    unsigned long long pk = 0; int s = 0;
    for (int kh = 0; kh < 4; ++kh) {
        if (((py + 1 - kh) & 1) != 0) continue;
        int dy = (py + 1 - kh) / 2;
        for (int kw = 0; kw < 4; ++kw) {
            if (((px + 1 - kw) & 1) != 0) continue;
            int dx = (px + 1 - kw) / 2;
            unsigned e = ((unsigned)(dy + 1) << 8) | ((unsigned)(dx + 1) << 4) | (unsigned)(kh * 4 + kw);
            pk |= (unsigned long long)e << (16 * s); ++s;
        }
    }
    return pk;
}

extern "C" void kernel_launch(void* const* d_in, const int* in_sizes, int n_in,
                              void* d_out, int out_size, void* d_ws, size_t ws_size,
                              hipStream_t stream) {
    const float* x       = (const float*)d_in[0];
    const float* w_enc1  = (const float*)d_in[1];
    const float* b_enc1  = (const float*)d_in[2];
    const float* w_enc2  = (const float*)d_in[3];
    const float* b_enc2  = (const float*)d_in[4];
    const float* w_prevq = (const float*)d_in[5];
    const float* b_prevq = (const float*)d_in[6];
    const float* emb     = (const float*)d_in[7];
    const float* w_post  = (const float*)d_in[8];
    const float* b_post  = (const float*)d_in[9];
    const float* w_dec1  = (const float*)d_in[10];
    const float* b_dec1  = (const float*)d_in[11];
    const float* w_dec2  = (const float*)d_in[12];
    const float* b_dec2  = (const float*)d_in[13];

    float* out = (float*)d_out;
    float* xr  = out;                     // 3,145,728
    float* ze  = out + 3145728;           // 16,777,216
    float* zq  = ze + 16777216;           // 16,777,216
    float* ppl = zq + 16777216;           // 1

    // ---- workspace carve (bytes) ----
    char* W = (char*)d_ws;
    float* wd2t = (float*)(W + 16384);      // dec2 fp32 [tap][ci][co]    7 KB
    float* esq  = (float*)(W + 24576);      // 2 KB
    int*   hist = (int*)(W + 28672);        // 2 KB
    bfraw* zp   = (bfraw*)(W + 32768);      // zero page, 256 B
    bfraw* w2b  = (bfraw*)(W + 560128);     // enc2  bf16 [co][16][64]   256 KB
    bfraw* w3b  = (bfraw*)(W + 822272);     // prevq bf16 [co][9][128]   576 KB
    bfraw* wpb  = (bfraw*)(W + 1412096);    // post  bf16 [co][16][256]  1 MB
    bfraw* wd1b = (bfraw*)(W + 2460672);    // dec1  bf16 [co][16][128]  256 KB
    bfraw* wb1  = (bfraw*)(W + 2722816);    // enc1  bf16 [co][64]        8 KB
    bfraw* embB = (bfraw*)(W + 2736128);    // emb   bf16 [512][256]    256 KB
    // bufX (128 MiB @ +4 MiB): sequential lifetimes
    //   a0 [0,33.5M) -> h2 [0,16.8M) -> zeb [16.8M,50.3M) -> zqb [50.3M,83.9M)
    //   -> ddec1 [0,134.2M)
    char* bufX = W + 4194304;
    bfraw* a0    = (bfraw*)bufX;
    bfraw* h2    = (bfraw*)bufX;
    bfraw* zeb   = (bfraw*)(bufX + 16777216);
    bfraw* zqb   = (bfraw*)(bufX + 50331648);
    bfraw* ddec1 = (bfraw*)bufX;
    // bufY (67.1 MB): dpost
    bfraw* dpost = (bfraw*)(W + 138412032);
    bfraw* h1    = (bfraw*)ze;              // alias: h1 dies before prevq writes z_e

    // ---- weight transforms + precomputes ----
    wt_kernel<<<8, 256, 0, stream>>>(w_dec2, wd2t, 3, 64, 3, 3, 1);
    wb1_kernel<<<16, 256, 0, stream>>>(w_enc1, wb1);
    wtb_kernel<<<512, 256, 0, stream>>>(w_enc2, w2b, 128, 64, 4, 4, 0);
    wtb_kernel<<<1152, 256, 0, stream>>>(w_prevq, w3b, 256, 128, 3, 3, 0);
    wtb_kernel<<<2048, 256, 0, stream>>>(w_post, wpb, 128, 256, 4, 4, 1);
    wtb_kernel<<<512, 256, 0, stream>>>(w_dec1, wd1b, 64, 128, 4, 4, 1);
    wtb_kernel<<<512, 256, 0, stream>>>(emb, embB, 512, 256, 1, 1, 0);
    embsq_kernel<<<512, 64, 0, stream>>>(emb, esq);
    hipMemsetAsync(hist, 0, 512 * sizeof(int), stream);
    hipMemsetAsync(zp, 0, 256, stream);

    // ---- encoder ----
    xpack_kernel<<<1024, 256, 0, stream>>>(x, a0);
    igemm_kernel<256, 64, 4, 1, false, true, false, false><<<dim3(1024, 1), 256, 0, stream>>>(
        a0, wb1, b_enc1, h1, nullptr, zp, 512, 512, 64, 1, 1, 2, 9, 9, 64, 1, 0, 0, 0, 0ULL);
    igemm_kernel<128, 128, 2, 2, false, true, false, false><<<dim3(512, 1), 256, 0, stream>>>(
        h1, w2b, b_enc2, h2, nullptr, zp, 128, 128, 64, 2, 16, 32, 6, 6, 128, 4, 1, 0, 0, 0ULL);
    // prevq: dual output ze fp32 + zeb bf16
    igemm_kernel<128, 128, 2, 2, false, false, true, true><<<dim3(512, 2), 256, 0, stream>>>(
        h2, w3b, b_prevq, ze, zeb, zp, 64, 64, 128, 1, 9, 36, 6, 6, 256, 3, 1, 0, 0, 0ULL);

    // ---- VQ (MFMA) ----
    vqm_kernel<<<512, 256, 0, stream>>>(zeb, embB, esq, emb, zq, zqb, hist);
    ppl_kernel<<<1, 512, 0, stream>>>(hist, ppl);

    // ---- decoder ----
    for (int cls = 0; cls < 4; ++cls) {
        int py = cls >> 1, px = cls & 1;
        igemm_kernel<128, 128, 2, 2, true, false, false, false><<<dim3(512, 1), 256, 0, stream>>>(
            zqb, wpb, b_post, dpost, nullptr, zp, 64, 64, 256, 1, 16, 32, 6, 6, 128, 4, 1,
            py, px, packFor(py, px));
    }
    for (int cls = 0; cls < 4; ++cls) {
        int py = cls >> 1, px = cls & 1;
        igemm_kernel<256, 64, 4, 1, true, true, false, false><<<dim3(1024, 1), 256, 0, stream>>>(
            dpost, wd1b, b_dec1, ddec1, nullptr, zp, 128, 128, 128, 1, 16, 16, 7, 7, 64, 4, 1,
            py, px, packFor(py, px));
    }
    dec2_kernel<<<1024, 256, 0, stream>>>(ddec1, wd2t, b_dec2, xr, zp);
}

// Round 2
// 958.727 us; speedup vs baseline: 1.0857x; 1.0857x over previous
//
#include <hip/hip_runtime.h>
#include <stdint.h>

// ---------------------------------------------------------------------------
// VQ-VAE forward on MI355X. Round 6: dec2 re-fix. R5's 8-channel chunking
// caused 3.6x HBM over-fetch (545 MB, 16B-of-128B line utilization per pass,
// L2 evictions between passes) -> dec2 HBM-bound at 184 us. R6: 16x16 output
// tile, stage FULL 64ch of the 18x18 halo (41.5 KB LDS, single buffer, one
// barrier), every 128B pixel record read exactly once, contiguous rows.
// 128B px record == 32 banks -> XOR-swizzle sub-slot by (px&7) on BOTH sides
// (pre-swizzled per-lane global source + swizzled LDS read, rule #21).
// 1 px/thread, 3 accs. Rest identical to R5.
// ---------------------------------------------------------------------------

typedef unsigned short bfraw;
typedef __attribute__((ext_vector_type(8))) short s16x8;
typedef __attribute__((ext_vector_type(4))) float f32x4;

__device__ __forceinline__ float bflo(unsigned int u) {
    union { unsigned int i; float f; } v; v.i = u << 16; return v.f;
}
__device__ __forceinline__ float bfhi(unsigned int u) {
    union { unsigned int i; float f; } v; v.i = u & 0xFFFF0000u; return v.f;
}
__device__ __forceinline__ bfraw f2bf(float f) {
    union { float f; unsigned int i; } v; v.f = f;
    unsigned int r = v.i + 0x7FFFu + ((v.i >> 16) & 1u);   // RNE
    return (bfraw)(r >> 16);
}

// async 16B global->LDS. LDS dest: wave-uniform base + lane*16; global src per-lane.
__device__ __forceinline__ void gl_lds16(const void* g, void* l) {
    auto gp = reinterpret_cast<const __attribute__((address_space(1))) unsigned int*>(
        reinterpret_cast<uintptr_t>(g));
    auto lp = reinterpret_cast<__attribute__((address_space(3))) unsigned int*>(
        reinterpret_cast<uintptr_t>(l));
    __builtin_amdgcn_global_load_lds(gp, lp, 16, 0, 0);
}

// --- weight transform (fp32, [tap][ci][co]) for dec2
__global__ void wt_kernel(const float* __restrict__ w, float* __restrict__ wt,
                          int Cout, int Cin, int KH, int KW, int transposed) {
    int n = Cout * Cin * KH * KW;
    for (int i = blockIdx.x * blockDim.x + threadIdx.x; i < n; i += gridDim.x * blockDim.x) {
        int co = i % Cout; int t = i / Cout;
        int ci = t % Cin;  int tap = t / Cin;
        int kw = tap % KW; int kh = tap / KW;
        float v = transposed ? w[(((long)ci * Cout + co) * KH + kh) * KW + kw]
                             : w[(((long)co * Cin + ci) * KH + kh) * KW + kw];
        wt[i] = v;
    }
}

// --- weight transform (bf16, [co][tap][ci]) for MFMA convs (B as [n][k]);
//     with KH=KW=1 also converts emb[512][256] to bf16 B layout.
__global__ void wtb_kernel(const float* __restrict__ w, bfraw* __restrict__ wt,
                           int Cout, int Cin, int KH, int KW, int transposed) {
    int n = Cout * Cin * KH * KW;
    int NT = KH * KW;
    for (int i = blockIdx.x * blockDim.x + threadIdx.x; i < n; i += gridDim.x * blockDim.x) {
        int ci = i % Cin; int t = i / Cin;
        int tap = t % NT; int co = t / NT;
        int kh = tap / KW, kw = tap % KW;
        float v = transposed ? w[(((long)ci * Cout + co) * KH + kh) * KW + kw]
                             : w[(((long)co * Cin + ci) * KH + kh) * KW + kw];
        wt[i] = f2bf(v);
    }
}

// --- enc1 weight pack: wb1[co][k64], k=(kh*4+kw)*3+ci (48 real, 16 zero)
__global__ void wb1_kernel(const float* __restrict__ w, bfraw* __restrict__ wt) {
    int i = blockIdx.x * 256 + threadIdx.x;
    if (i >= 4096) return;
    int k = i & 63, co = i >> 6;
    bfraw v = 0;
    if (k < 48) {
        int ci = k % 3, tap = k / 3, kh = tap >> 2, kw = tap & 3;
        v = f2bf(w[(((long)co * 3 + ci) * 4 + kh) * 4 + kw]);
    }
    wt[(long)co * 64 + k] = v;
}

// --- enc1 im2col: x NCHW fp32 -> A0[pos][64] bf16 (48 patch vals + 16 zeros)
__global__ __launch_bounds__(256) void xpack_kernel(const float* __restrict__ x,
                                                    bfraw* __restrict__ a0) {
    int pos = blockIdx.x * 256 + threadIdx.x;        // 262144
    int ow = pos & 127, oh = (pos >> 7) & 127, n = pos >> 14;
    __align__(16) bfraw v[64];
#pragma unroll
    for (int i = 0; i < 64; ++i) v[i] = 0;
#pragma unroll
    for (int kh = 0; kh < 4; ++kh) {
        int ih = 2 * oh - 1 + kh; if ((unsigned)ih >= 256u) continue;
#pragma unroll
        for (int kw = 0; kw < 4; ++kw) {
            int iw = 2 * ow - 1 + kw; if ((unsigned)iw >= 256u) continue;
#pragma unroll
            for (int ci = 0; ci < 3; ++ci)
                v[(kh * 4 + kw) * 3 + ci] =
                    f2bf(x[(((long)n * 3 + ci) * 256 + ih) * 256 + iw]);
        }
    }
    uint4* dst = (uint4*)(a0 + (long)pos * 64);
    const uint4* src = (const uint4*)v;
#pragma unroll
    for (int i = 0; i < 8; ++i) dst[i] = src[i];
}

// --- emb row norms
__global__ void embsq_kernel(const float* __restrict__ emb, float* __restrict__ esq) {
    int k = blockIdx.x, lane = threadIdx.x;
    float s = 0.f;
    for (int d = lane; d < 256; d += 64) { float v = emb[k * 256 + d]; s += v * v; }
    for (int o = 32; o; o >>= 1) s += __shfl_down(s, o, 64);
    if (lane == 0) esq[k] = s;
}

// ---------------------------------------------------------------------------
// MFMA implicit GEMM. C[MxN] = A[MxK]*B[KxN].
// ---------------------------------------------------------------------------
template<int BM, int BN, int WM, int WN, bool TR, bool RELU, bool OUTF32, bool DUALB>
__global__ __launch_bounds__(256) void igemm_kernel(
    const bfraw* __restrict__ in, const bfraw* __restrict__ wt,
    const float* __restrict__ bias, void* __restrict__ outv,
    bfraw* __restrict__ outb, const bfraw* __restrict__ zp,
    int Hin, int Win, int Cin, int sf, int NTW, int Ksteps,
    int lw, int lh, int N, int KW, int pad, int py, int px,
    unsigned long long pack)
{
    constexpr int APASS = BM / 64, BPASS = BN / 64;
    __shared__ __align__(16) bfraw ldsA[BM * 32];
    __shared__ __align__(16) bfraw ldsB[BN * 32];
    const int tid = threadIdx.x, lane = tid & 63, wv = tid >> 6;
    const int wm = wv / WN, wn = wv % WN;
    const int lrow = lane >> 2, lkof = (lane & 3) * 8;
    const int blockM = blockIdx.x, n0 = blockIdx.y * BN;
    const int Wm1 = (1 << lw) - 1, Hm1 = (1 << lh) - 1;

    long baseA[APASS]; int ihb[APASS], iwb[APASS];
#pragma unroll
    for (int p = 0; p < APASS; ++p) {
        int m = p * 64 + wv * 16 + lrow;
        int pos = blockM * BM + m;
        int ow = pos & Wm1; int t = pos >> lw;
        int oh = t & Hm1;   int nb = t >> lh;
        ihb[p] = oh * sf; iwb[p] = ow * sf;
        baseA[p] = ((long)(nb * Hin + ihb[p]) * Win + iwb[p]) * (long)Cin + lkof;
    }
    long baseB[BPASS];
#pragma unroll
    for (int p = 0; p < BPASS; ++p) {
        int nl = p * 64 + wv * 16 + lrow;
        baseB[p] = (long)(n0 + nl) * ((long)NTW * Cin) + lkof;
    }

    f32x4 acc[4][4];
#pragma unroll
    for (int i = 0; i < 4; ++i)
#pragma unroll
        for (int j = 0; j < 4; ++j) acc[i][j] = (f32x4)0.f;

    int ci0 = 0, tslot = 0, dy, dx, wk;
    if (TR) {
        unsigned e = (unsigned)pack & 0xFFFFu;
        dy = (int)((e >> 8) & 3) - 1; dx = (int)((e >> 4) & 3) - 1; wk = (int)(e & 15u);
    } else { dy = -pad; dx = -pad; wk = 0; }

    const int quad = lane >> 4, r16 = lane & 15;

    for (int ks = 0; ks < Ksteps; ++ks) {
        long offA = ((long)(dy * Win + dx)) * Cin + ci0;
        long offB = (long)wk * Cin + ci0;
#pragma unroll
        for (int p = 0; p < APASS; ++p) {
            int ih = ihb[p] + dy, iw = iwb[p] + dx;
            bool ok = ((unsigned)ih < (unsigned)Hin) & ((unsigned)iw < (unsigned)Win);
            const bfraw* g = ok ? (in + baseA[p] + offA) : (zp + lkof);
            gl_lds16(g, &ldsA[(p * 64 + wv * 16) * 32]);
        }
#pragma unroll
        for (int p = 0; p < BPASS; ++p)
            gl_lds16(wt + baseB[p] + offB, &ldsB[(p * 64 + wv * 16) * 32]);
        __syncthreads();
        s16x8 af[4], bf[4];
#pragma unroll
        for (int i = 0; i < 4; ++i)
            af[i] = *(const s16x8*)&ldsA[(wm * 64 + i * 16 + r16) * 32 + quad * 8];
#pragma unroll
        for (int j = 0; j < 4; ++j)
            bf[j] = *(const s16x8*)&ldsB[(wn * 64 + j * 16 + r16) * 32 + quad * 8];
#pragma unroll
        for (int i = 0; i < 4; ++i)
#pragma unroll
            for (int j = 0; j < 4; ++j)
                acc[i][j] = __builtin_amdgcn_mfma_f32_16x16x32_bf16(af[i], bf[j], acc[i][j], 0, 0, 0);
        __syncthreads();
        ci0 += 32;
        if (ci0 == Cin) {
            ci0 = 0; ++tslot;
            if (TR) {
                unsigned e = (unsigned)(pack >> (tslot * 16)) & 0xFFFFu;
                dy = (int)((e >> 8) & 3) - 1; dx = (int)((e >> 4) & 3) - 1; wk = (int)(e & 15u);
            } else { ++wk; ++dx; if (dx == KW - pad) { dx = -pad; ++dy; } }
        }
    }

#pragma unroll
    for (int j = 0; j < 4; ++j) {
        int col = wn * 64 + j * 16 + r16; int ng = n0 + col;
        float bv = bias[ng];
#pragma unroll
        for (int i = 0; i < 4; ++i) {
            int mb = wm * 64 + i * 16 + quad * 4;
#pragma unroll
            for (int r = 0; r < 4; ++r) {
                int pos2 = blockM * BM + mb + r;
                long oaddr;
                if (TR) {
                    int ow2 = pos2 & Wm1; int t = pos2 >> lw;
                    int oh2 = t & Hm1;    int nb = t >> lh;
                    int oh = 2 * oh2 + py, ow = 2 * ow2 + px;
                    oaddr = ((long)(((nb << (lh + 1)) + oh) << (lw + 1)) + ow) * N + ng;
                } else {
                    oaddr = (long)pos2 * N + ng;
                }
                float v = acc[i][j][r] + bv;
                if (RELU) v = fmaxf(v, 0.f);
                if (OUTF32) {
                    ((float*)outv)[oaddr] = v;
                    if (DUALB) outb[oaddr] = f2bf(v);
                } else {
                    ((bfraw*)outv)[oaddr] = f2bf(v);
                }
            }
        }
    }
}

// ---------------------------------------------------------------------------
// dec2: convT k3 s1 p1, 64->3ch, fp32 NCHW out.
// Block = 16x16 output tile (grid 16 n * 256 tiles = 4096). Thread = 1 px.
// Full-channel staging: 18x18 halo x 64ch = 41,472 B LDS, single buffer, ONE
// barrier. Each 128B pixel record fetched exactly once (rows contiguous).
// 128B record == 32 banks -> sub-slot XOR swizzle by (px&7): stage reads
// global sub-seg (d ^ (px&7)) into linear LDS slot d (per-lane global src,
// wave-linear LDS dest), compute reads slot (j ^ (px&7)) for channel block j.
// OOB halo -> zero page. Weights: uniform -> scalar loads.
// ---------------------------------------------------------------------------
__global__ __launch_bounds__(256) void dec2_kernel(
    const bfraw* __restrict__ in, const float* __restrict__ wt,
    const float* __restrict__ bias, float* __restrict__ out,
    const bfraw* __restrict__ zp) {
    __shared__ __align__(16) bfraw tile[18 * 18 * 64];   // 41,472 B
    const int tid = threadIdx.x;
    const int b = blockIdx.x;
    const int n = b >> 8, t8 = b & 255;
    const int r0 = (t8 >> 4) * 16, c0 = (t8 & 15) * 16;
    const int wv = tid >> 6;
    const long nbase = (long)n * 65536;                  // px index base of image

    // ---- stage: 2592 segs of 16B (10 full passes + 32 tail) ----
#pragma unroll
    for (int k = 0; k < 10; ++k) {
        int t = k * 256 + tid;
        int px = t >> 3, d = t & 7;
        int pr = px / 18, pc = px - pr * 18;
        int ih = r0 - 1 + pr, iw = c0 - 1 + pc;
        bool ok = ((unsigned)ih < 256u) & ((unsigned)iw < 256u);
        int s = d ^ (px & 7);                            // pre-swizzled source sub-seg
        const bfraw* g = ok ? in + ((nbase + (long)ih * 256 + iw) << 6) + s * 8 : zp;
        gl_lds16(g, &tile[(k * 256 + wv * 64) * 8]);
    }
    if (tid < 32) {
        int t = 2560 + tid;
        int px = t >> 3, d = t & 7;
        int pr = px / 18, pc = px - pr * 18;
        int ih = r0 - 1 + pr, iw = c0 - 1 + pc;
        bool ok = ((unsigned)ih < 256u) & ((unsigned)iw < 256u);
        int s = d ^ (px & 7);
        const bfraw* g = ok ? in + ((nbase + (long)ih * 256 + iw) << 6) + s * 8 : zp;
        gl_lds16(g, &tile[2560 * 8]);
    }
    __syncthreads();

    // ---- compute: 1 output px per thread ----
    const int pr_out = tid >> 4, pc_out = tid & 15;
    float a0 = bias[0], a1 = bias[1], a2 = bias[2];
#pragma unroll
    for (int kh = 0; kh < 3; ++kh) {
#pragma unroll
        for (int kw = 0; kw < 3; ++kw) {
            const int q = (pr_out + 2 - kh) * 18 + (pc_out + 2 - kw);
            const int q7 = q & 7;
            const float* w0 = wt + (kh * 3 + kw) * 192;
#pragma unroll
            for (int j = 0; j < 8; ++j) {               // channel block j (ch 8j..8j+7)
                uint4 u = *(const uint4*)&tile[(q * 8 + (j ^ q7)) * 8];
                const float* wd = w0 + j * 24;
                float v0 = bflo(u.x), v1 = bfhi(u.x);
                float v2 = bflo(u.y), v3 = bfhi(u.y);
                float v4 = bflo(u.z), v5 = bfhi(u.z);
                float v6 = bflo(u.w), v7 = bfhi(u.w);
                a0 = fmaf(v0, wd[0],  a0); a1 = fmaf(v0, wd[1],  a1); a2 = fmaf(v0, wd[2],  a2);
                a0 = fmaf(v1, wd[3],  a0); a1 = fmaf(v1, wd[4],  a1); a2 = fmaf(v1, wd[5],  a2);
                a0 = fmaf(v2, wd[6],  a0); a1 = fmaf(v2, wd[7],  a1); a2 = fmaf(v2, wd[8],  a2);
                a0 = fmaf(v3, wd[9],  a0); a1 = fmaf(v3, wd[10], a1); a2 = fmaf(v3, wd[11], a2);
                a0 = fmaf(v4, wd[12], a0); a1 = fmaf(v4, wd[13], a1); a2 = fmaf(v4, wd[14], a2);
                a0 = fmaf(v5, wd[15], a0); a1 = fmaf(v5, wd[16], a1); a2 = fmaf(v5, wd[17], a2);
                a0 = fmaf(v6, wd[18], a0); a1 = fmaf(v6, wd[19], a1); a2 = fmaf(v6, wd[20], a2);
                a0 = fmaf(v7, wd[21], a0); a1 = fmaf(v7, wd[22], a1); a2 = fmaf(v7, wd[23], a2);
            }
        }
    }

    const int oh = r0 + pr_out, ow = c0 + pc_out;
    const long sp = (long)n * 196608;
    const long hw = (long)oh * 256 + ow;
    out[sp + hw] = a0; out[sp + 65536 + hw] = a1; out[sp + 131072 + hw] = a2;
}

// ---------------------------------------------------------------------------
// VQ via MFMA: S = Zb[128 x 256] x EbT (codes as B rows), dist = ||e||^2 - 2S.
// Two waves share each 64-row group (different code halves): partial argmins
// are merged via LDS before ONE sIdx write + ONE hist atomic per row.
// ---------------------------------------------------------------------------
__global__ __launch_bounds__(256) void vqm_kernel(
    const bfraw* __restrict__ zeb, const bfraw* __restrict__ embB,
    const float* __restrict__ esq, const float* __restrict__ emb,
    float* __restrict__ zq, bfraw* __restrict__ zqb, int* __restrict__ hist)
{
    __shared__ __align__(16) bfraw ldsA[128 * 32];
    __shared__ __align__(16) bfraw ldsB[128 * 32];
    __shared__ float sEsq[512];
    __shared__ float sVal[2][128];
    __shared__ int   sKey[2][128];
    __shared__ int   sIdx[128];
    const int tid = threadIdx.x, lane = tid & 63, wv = tid >> 6;
    const int wm = wv >> 1, wn = wv & 1;
    const int lrow = lane >> 2, lkof = (lane & 3) * 8;
    const int quad = lane >> 4, r16 = lane & 15;
    const int posBase = blockIdx.x * 128;

    for (int i = tid; i < 512; i += 256) sEsq[i] = esq[i];

    const long baseA0 = (long)(posBase + wv * 16 + lrow) * 256 + lkof;
    const long baseA1 = baseA0 + 64 * 256;

    float bestv[16]; int bestk[16];
#pragma unroll
    for (int t = 0; t < 16; ++t) { bestv[t] = 1e30f; bestk[t] = 1 << 30; }

    for (int chunk = 0; chunk < 4; ++chunk) {
        f32x4 acc[4][4];
#pragma unroll
        for (int i = 0; i < 4; ++i)
#pragma unroll
            for (int j = 0; j < 4; ++j) acc[i][j] = (f32x4)0.f;
        const long baseB0 = (long)(chunk * 128 + wv * 16 + lrow) * 256 + lkof;
        const long baseB1 = baseB0 + 64 * 256;
        for (int k = 0; k < 8; ++k) {
            gl_lds16(zeb + baseA0 + k * 32, &ldsA[(wv * 16) * 32]);
            gl_lds16(zeb + baseA1 + k * 32, &ldsA[(64 + wv * 16) * 32]);
            gl_lds16(embB + baseB0 + k * 32, &ldsB[(wv * 16) * 32]);
            gl_lds16(embB + baseB1 + k * 32, &ldsB[(64 + wv * 16) * 32]);
            __syncthreads();
            s16x8 af[4], bf[4];
#pragma unroll
            for (int i = 0; i < 4; ++i)
                af[i] = *(const s16x8*)&ldsA[(wm * 64 + i * 16 + r16) * 32 + quad * 8];
#pragma unroll
            for (int j = 0; j < 4; ++j)
                bf[j] = *(const s16x8*)&ldsB[(wn * 64 + j * 16 + r16) * 32 + quad * 8];
#pragma unroll
            for (int i = 0; i < 4; ++i)
#pragma unroll
                for (int j = 0; j < 4; ++j)
                    acc[i][j] = __builtin_amdgcn_mfma_f32_16x16x32_bf16(af[i], bf[j], acc[i][j], 0, 0, 0);
            __syncthreads();
        }
        // chunk epilogue: dist + argmin. C row = i*16 + quad*4 + r, col = r16.
#pragma unroll
        for (int i = 0; i < 4; ++i) {
#pragma unroll
            for (int r = 0; r < 4; ++r) {
                float v = 1e30f; int kk = 1 << 30;
#pragma unroll
                for (int j = 0; j < 4; ++j) {
                    int code = chunk * 128 + wn * 64 + j * 16 + r16;
                    float d = sEsq[code] - 2.f * acc[i][j][r];
                    if (d < v || (d == v && code < kk)) { v = d; kk = code; }
                }
#pragma unroll
                for (int m = 1; m < 16; m <<= 1) {
                    float ov = __shfl_xor(v, m, 64);
                    int   ok = __shfl_xor(kk, m, 64);
                    if (ov < v || (ov == v && ok < kk)) { v = ov; kk = ok; }
                }
                int s = i * 4 + r;
                if (v < bestv[s] || (v == bestv[s] && kk < bestk[s])) {
                    bestv[s] = v; bestk[s] = kk;
                }
            }
        }
    }
    // publish per-wave partials (each wave covered half the codes for its rows)
    if (r16 == 0) {
#pragma unroll
        for (int i = 0; i < 4; ++i)
#pragma unroll
            for (int r = 0; r < 4; ++r) {
                int localRow = wm * 64 + i * 16 + quad * 4 + r;
                int s = i * 4 + r;
                sVal[wn][localRow] = bestv[s];
                sKey[wn][localRow] = bestk[s];
            }
    }
    __syncthreads();
    // merge halves: one thread per row, single sIdx write + single hist atomic
    if (tid < 128) {
        float v0 = sVal[0][tid]; int k0 = sKey[0][tid];
        float v1 = sVal[1][tid]; int k1 = sKey[1][tid];
        int kk = (v1 < v0 || (v1 == v0 && k1 < k0)) ? k1 : k0;
        sIdx[tid] = kk;
        atomicAdd(&hist[kk], 1);
    }
    __syncthreads();
    const float4* emb4 = (const float4*)emb;
    float4*  zq4  = (float4*)(zq + (long)posBase * 256);
    ushort4* zqb4 = (ushort4*)(zqb + (long)posBase * 256);
    for (int i2 = tid; i2 < 128 * 64; i2 += 256) {
        int p = i2 >> 6, c = i2 & 63;
        float4 vv = emb4[sIdx[p] * 64 + c];
        zq4[i2] = vv;
        ushort4 u; u.x = f2bf(vv.x); u.y = f2bf(vv.y); u.z = f2bf(vv.z); u.w = f2bf(vv.w);
        zqb4[i2] = u;
    }
}

// --- perplexity
__global__ void ppl_kernel(const int* __restrict__ hist, float* __restrict__ outp) {
    __shared__ float red[512];
    int t = threadIdx.x;
    float p = (float)hist[t] * (1.0f / 65536.0f);
    red[t] = p * logf(p + 1e-10f);
    __syncthreads();
    for (int s = 256; s; s >>= 1) { if (t < s) red[t] += red[t + s]; __syncthreads(); }
    if (t == 0) *outp = expf(-red[0]);
}

// host: pack convT parity-class tap table (4 entries x 16 bits)
static unsigned long long packFor(int py, int px) {
    unsigned long long pk = 0; int s = 0;
    for (int kh = 0; kh < 4; ++kh) {
        if (((py + 1 - kh) & 1) != 0) continue;
        int dy = (py + 1 - kh) / 2;
        for (int kw = 0; kw < 4; ++kw) {
            if (((px + 1 - kw) & 1) != 0) continue;
            int dx = (px + 1 - kw) / 2;
            unsigned e = ((unsigned)(dy + 1) << 8) | ((unsigned)(dx + 1) << 4) | (unsigned)(kh * 4 + kw);
            pk |= (unsigned long long)e << (16 * s); ++s;
        }
    }
    return pk;
}

extern "C" void kernel_launch(void* const* d_in, const int* in_sizes, int n_in,
                              void* d_out, int out_size, void* d_ws, size_t ws_size,
                              hipStream_t stream) {
    const float* x       = (const float*)d_in[0];
    const float* w_enc1  = (const float*)d_in[1];
    const float* b_enc1  = (const float*)d_in[2];
    const float* w_enc2  = (const float*)d_in[3];
    const float* b_enc2  = (const float*)d_in[4];
    const float* w_prevq = (const float*)d_in[5];
    const float* b_prevq = (const float*)d_in[6];
    const float* emb     = (const float*)d_in[7];
    const float* w_post  = (const float*)d_in[8];
    const float* b_post  = (const float*)d_in[9];
    const float* w_dec1  = (const float*)d_in[10];
    const float* b_dec1  = (const float*)d_in[11];
    const float* w_dec2  = (const float*)d_in[12];
    const float* b_dec2  = (const float*)d_in[13];

    float* out = (float*)d_out;
    float* xr  = out;                     // 3,145,728
    float* ze  = out + 3145728;           // 16,777,216
    float* zq  = ze + 16777216;           // 16,777,216
    float* ppl = zq + 16777216;           // 1

    // ---- workspace carve (bytes) ----
    char* W = (char*)d_ws;
    float* wd2t = (float*)(W + 16384);      // dec2 fp32 [tap][ci][co]    7 KB
    float* esq  = (float*)(W + 24576);      // 2 KB
    int*   hist = (int*)(W + 28672);        // 2 KB
    bfraw* zp   = (bfraw*)(W + 32768);      // zero page, 256 B
    bfraw* w2b  = (bfraw*)(W + 560128);     // enc2  bf16 [co][16][64]   256 KB
    bfraw* w3b  = (bfraw*)(W + 822272);     // prevq bf16 [co][9][128]   576 KB
    bfraw* wpb  = (bfraw*)(W + 1412096);    // post  bf16 [co][16][256]  1 MB
    bfraw* wd1b = (bfraw*)(W + 2460672);    // dec1  bf16 [co][16][128]  256 KB
    bfraw* wb1  = (bfraw*)(W + 2722816);    // enc1  bf16 [co][64]        8 KB
    bfraw* embB = (bfraw*)(W + 2736128);    // emb   bf16 [512][256]    256 KB
    // bufX (128 MiB @ +4 MiB): sequential lifetimes
    //   a0 [0,33.5M) -> h2 [0,16.8M) -> zeb [16.8M,50.3M) -> zqb [50.3M,83.9M)
    //   -> ddec1 [0,134.2M)
    char* bufX = W + 4194304;
    bfraw* a0    = (bfraw*)bufX;
    bfraw* h2    = (bfraw*)bufX;
    bfraw* zeb   = (bfraw*)(bufX + 16777216);
    bfraw* zqb   = (bfraw*)(bufX + 50331648);
    bfraw* ddec1 = (bfraw*)bufX;
    // bufY (67.1 MB): dpost
    bfraw* dpost = (bfraw*)(W + 138412032);
    bfraw* h1    = (bfraw*)ze;              // alias: h1 dies before prevq writes z_e

    // ---- weight transforms + precomputes ----
    wt_kernel<<<8, 256, 0, stream>>>(w_dec2, wd2t, 3, 64, 3, 3, 1);
    wb1_kernel<<<16, 256, 0, stream>>>(w_enc1, wb1);
    wtb_kernel<<<512, 256, 0, stream>>>(w_enc2, w2b, 128, 64, 4, 4, 0);
    wtb_kernel<<<1152, 256, 0, stream>>>(w_prevq, w3b, 256, 128, 3, 3, 0);
    wtb_kernel<<<2048, 256, 0, stream>>>(w_post, wpb, 128, 256, 4, 4, 1);
    wtb_kernel<<<512, 256, 0, stream>>>(w_dec1, wd1b, 64, 128, 4, 4, 1);
    wtb_kernel<<<512, 256, 0, stream>>>(emb, embB, 512, 256, 1, 1, 0);
    embsq_kernel<<<512, 64, 0, stream>>>(emb, esq);
    hipMemsetAsync(hist, 0, 512 * sizeof(int), stream);
    hipMemsetAsync(zp, 0, 256, stream);

    // ---- encoder ----
    xpack_kernel<<<1024, 256, 0, stream>>>(x, a0);
    igemm_kernel<256, 64, 4, 1, false, true, false, false><<<dim3(1024, 1), 256, 0, stream>>>(
        a0, wb1, b_enc1, h1, nullptr, zp, 512, 512, 64, 1, 1, 2, 9, 9, 64, 1, 0, 0, 0, 0ULL);
    igemm_kernel<128, 128, 2, 2, false, true, false, false><<<dim3(512, 1), 256, 0, stream>>>(
        h1, w2b, b_enc2, h2, nullptr, zp, 128, 128, 64, 2, 16, 32, 6, 6, 128, 4, 1, 0, 0, 0ULL);
    // prevq: dual output ze fp32 + zeb bf16
    igemm_kernel<128, 128, 2, 2, false, false, true, true><<<dim3(512, 2), 256, 0, stream>>>(
        h2, w3b, b_prevq, ze, zeb, zp, 64, 64, 128, 1, 9, 36, 6, 6, 256, 3, 1, 0, 0, 0ULL);

    // ---- VQ (MFMA) ----
    vqm_kernel<<<512, 256, 0, stream>>>(zeb, embB, esq, emb, zq, zqb, hist);
    ppl_kernel<<<1, 512, 0, stream>>>(hist, ppl);

    // ---- decoder ----
    for (int cls = 0; cls < 4; ++cls) {
        int py = cls >> 1, px = cls & 1;
        igemm_kernel<128, 128, 2, 2, true, false, false, false><<<dim3(512, 1), 256, 0, stream>>>(
            zqb, wpb, b_post, dpost, nullptr, zp, 64, 64, 256, 1, 16, 32, 6, 6, 128, 4, 1,
            py, px, packFor(py, px));
    }
    for (int cls = 0; cls < 4; ++cls) {
        int py = cls >> 1, px = cls & 1;
        igemm_kernel<256, 64, 4, 1, true, true, false, false><<<dim3(1024, 1), 256, 0, stream>>>(
            dpost, wd1b, b_dec1, ddec1, nullptr, zp, 128, 128, 128, 1, 16, 16, 7, 7, 64, 4, 1,
            py, px, packFor(py, px));
    }
    dec2_kernel<<<4096, 256, 0, stream>>>(ddec1, wd2t, b_dec2, xr, zp);
}

// Round 3
// 933.522 us; speedup vs baseline: 1.1150x; 1.0270x over previous
//
#include <hip/hip_runtime.h>
#include <stdint.h>

// ---------------------------------------------------------------------------
// VQ-VAE forward on MI355X. Round 7: vqm rewrite. R6 vqm was barrier-bound
// (MfmaUtil 4.5%, VALUBusy 11%, HBM 14% — 64 barrier pairs/block with full
// vmcnt(0) drains, 16 MFMA between barriers, no staging overlap). R7: stage
// A[128x256] once + B per 128-code chunk (64KB+64KB LDS, XOR-swizzled
// d16^=row&7 both-sides), 8 ksteps x 16 MFMA barrier-free per chunk, B
// prefetch issued after the chunk barrier and hidden under the argmin
// epilogue (VALU), closing barrier's vmcnt drain completes it. 8 barriers
// total. Lane-reduce deferred out of the chunk loop. Rest identical to R6.
// ---------------------------------------------------------------------------

typedef unsigned short bfraw;
typedef __attribute__((ext_vector_type(8))) short s16x8;
typedef __attribute__((ext_vector_type(4))) float f32x4;

__device__ __forceinline__ float bflo(unsigned int u) {
    union { unsigned int i; float f; } v; v.i = u << 16; return v.f;
}
__device__ __forceinline__ float bfhi(unsigned int u) {
    union { unsigned int i; float f; } v; v.i = u & 0xFFFF0000u; return v.f;
}
__device__ __forceinline__ bfraw f2bf(float f) {
    union { float f; unsigned int i; } v; v.f = f;
    unsigned int r = v.i + 0x7FFFu + ((v.i >> 16) & 1u);   // RNE
    return (bfraw)(r >> 16);
}

// async 16B global->LDS. LDS dest: wave-uniform base + lane*16; global src per-lane.
__device__ __forceinline__ void gl_lds16(const void* g, void* l) {
    auto gp = reinterpret_cast<const __attribute__((address_space(1))) unsigned int*>(
        reinterpret_cast<uintptr_t>(g));
    auto lp = reinterpret_cast<__attribute__((address_space(3))) unsigned int*>(
        reinterpret_cast<uintptr_t>(l));
    __builtin_amdgcn_global_load_lds(gp, lp, 16, 0, 0);
}

// --- weight transform (fp32, [tap][ci][co]) for dec2
__global__ void wt_kernel(const float* __restrict__ w, float* __restrict__ wt,
                          int Cout, int Cin, int KH, int KW, int transposed) {
    int n = Cout * Cin * KH * KW;
    for (int i = blockIdx.x * blockDim.x + threadIdx.x; i < n; i += gridDim.x * blockDim.x) {
        int co = i % Cout; int t = i / Cout;
        int ci = t % Cin;  int tap = t / Cin;
        int kw = tap % KW; int kh = tap / KW;
        float v = transposed ? w[(((long)ci * Cout + co) * KH + kh) * KW + kw]
                             : w[(((long)co * Cin + ci) * KH + kh) * KW + kw];
        wt[i] = v;
    }
}

// --- weight transform (bf16, [co][tap][ci]) for MFMA convs (B as [n][k]);
//     with KH=KW=1 also converts emb[512][256] to bf16 B layout.
__global__ void wtb_kernel(const float* __restrict__ w, bfraw* __restrict__ wt,
                           int Cout, int Cin, int KH, int KW, int transposed) {
    int n = Cout * Cin * KH * KW;
    int NT = KH * KW;
    for (int i = blockIdx.x * blockDim.x + threadIdx.x; i < n; i += gridDim.x * blockDim.x) {
        int ci = i % Cin; int t = i / Cin;
        int tap = t % NT; int co = t / NT;
        int kh = tap / KW, kw = tap % KW;
        float v = transposed ? w[(((long)ci * Cout + co) * KH + kh) * KW + kw]
                             : w[(((long)co * Cin + ci) * KH + kh) * KW + kw];
        wt[i] = f2bf(v);
    }
}

// --- enc1 weight pack: wb1[co][k64], k=(kh*4+kw)*3+ci (48 real, 16 zero)
__global__ void wb1_kernel(const float* __restrict__ w, bfraw* __restrict__ wt) {
    int i = blockIdx.x * 256 + threadIdx.x;
    if (i >= 4096) return;
    int k = i & 63, co = i >> 6;
    bfraw v = 0;
    if (k < 48) {
        int ci = k % 3, tap = k / 3, kh = tap >> 2, kw = tap & 3;
        v = f2bf(w[(((long)co * 3 + ci) * 4 + kh) * 4 + kw]);
    }
    wt[(long)co * 64 + k] = v;
}

// --- enc1 im2col: x NCHW fp32 -> A0[pos][64] bf16 (48 patch vals + 16 zeros)
__global__ __launch_bounds__(256) void xpack_kernel(const float* __restrict__ x,
                                                    bfraw* __restrict__ a0) {
    int pos = blockIdx.x * 256 + threadIdx.x;        // 262144
    int ow = pos & 127, oh = (pos >> 7) & 127, n = pos >> 14;
    __align__(16) bfraw v[64];
#pragma unroll
    for (int i = 0; i < 64; ++i) v[i] = 0;
#pragma unroll
    for (int kh = 0; kh < 4; ++kh) {
        int ih = 2 * oh - 1 + kh; if ((unsigned)ih >= 256u) continue;
#pragma unroll
        for (int kw = 0; kw < 4; ++kw) {
            int iw = 2 * ow - 1 + kw; if ((unsigned)iw >= 256u) continue;
#pragma unroll
            for (int ci = 0; ci < 3; ++ci)
                v[(kh * 4 + kw) * 3 + ci] =
                    f2bf(x[(((long)n * 3 + ci) * 256 + ih) * 256 + iw]);
        }
    }
    uint4* dst = (uint4*)(a0 + (long)pos * 64);
    const uint4* src = (const uint4*)v;
#pragma unroll
    for (int i = 0; i < 8; ++i) dst[i] = src[i];
}

// --- emb row norms
__global__ void embsq_kernel(const float* __restrict__ emb, float* __restrict__ esq) {
    int k = blockIdx.x, lane = threadIdx.x;
    float s = 0.f;
    for (int d = lane; d < 256; d += 64) { float v = emb[k * 256 + d]; s += v * v; }
    for (int o = 32; o; o >>= 1) s += __shfl_down(s, o, 64);
    if (lane == 0) esq[k] = s;
}

// ---------------------------------------------------------------------------
// MFMA implicit GEMM. C[MxN] = A[MxK]*B[KxN].
// ---------------------------------------------------------------------------
template<int BM, int BN, int WM, int WN, bool TR, bool RELU, bool OUTF32, bool DUALB>
__global__ __launch_bounds__(256) void igemm_kernel(
    const bfraw* __restrict__ in, const bfraw* __restrict__ wt,
    const float* __restrict__ bias, void* __restrict__ outv,
    bfraw* __restrict__ outb, const bfraw* __restrict__ zp,
    int Hin, int Win, int Cin, int sf, int NTW, int Ksteps,
    int lw, int lh, int N, int KW, int pad, int py, int px,
    unsigned long long pack)
{
    constexpr int APASS = BM / 64, BPASS = BN / 64;
    __shared__ __align__(16) bfraw ldsA[BM * 32];
    __shared__ __align__(16) bfraw ldsB[BN * 32];
    const int tid = threadIdx.x, lane = tid & 63, wv = tid >> 6;
    const int wm = wv / WN, wn = wv % WN;
    const int lrow = lane >> 2, lkof = (lane & 3) * 8;
    const int blockM = blockIdx.x, n0 = blockIdx.y * BN;
    const int Wm1 = (1 << lw) - 1, Hm1 = (1 << lh) - 1;

    long baseA[APASS]; int ihb[APASS], iwb[APASS];
#pragma unroll
    for (int p = 0; p < APASS; ++p) {
        int m = p * 64 + wv * 16 + lrow;
        int pos = blockM * BM + m;
        int ow = pos & Wm1; int t = pos >> lw;
        int oh = t & Hm1;   int nb = t >> lh;
        ihb[p] = oh * sf; iwb[p] = ow * sf;
        baseA[p] = ((long)(nb * Hin + ihb[p]) * Win + iwb[p]) * (long)Cin + lkof;
    }
    long baseB[BPASS];
#pragma unroll
    for (int p = 0; p < BPASS; ++p) {
        int nl = p * 64 + wv * 16 + lrow;
        baseB[p] = (long)(n0 + nl) * ((long)NTW * Cin) + lkof;
    }

    f32x4 acc[4][4];
#pragma unroll
    for (int i = 0; i < 4; ++i)
#pragma unroll
        for (int j = 0; j < 4; ++j) acc[i][j] = (f32x4)0.f;

    int ci0 = 0, tslot = 0, dy, dx, wk;
    if (TR) {
        unsigned e = (unsigned)pack & 0xFFFFu;
        dy = (int)((e >> 8) & 3) - 1; dx = (int)((e >> 4) & 3) - 1; wk = (int)(e & 15u);
    } else { dy = -pad; dx = -pad; wk = 0; }

    const int quad = lane >> 4, r16 = lane & 15;

    for (int ks = 0; ks < Ksteps; ++ks) {
        long offA = ((long)(dy * Win + dx)) * Cin + ci0;
        long offB = (long)wk * Cin + ci0;
#pragma unroll
        for (int p = 0; p < APASS; ++p) {
            int ih = ihb[p] + dy, iw = iwb[p] + dx;
            bool ok = ((unsigned)ih < (unsigned)Hin) & ((unsigned)iw < (unsigned)Win);
            const bfraw* g = ok ? (in + baseA[p] + offA) : (zp + lkof);
            gl_lds16(g, &ldsA[(p * 64 + wv * 16) * 32]);
        }
#pragma unroll
        for (int p = 0; p < BPASS; ++p)
            gl_lds16(wt + baseB[p] + offB, &ldsB[(p * 64 + wv * 16) * 32]);
        __syncthreads();
        s16x8 af[4], bf[4];
#pragma unroll
        for (int i = 0; i < 4; ++i)
            af[i] = *(const s16x8*)&ldsA[(wm * 64 + i * 16 + r16) * 32 + quad * 8];
#pragma unroll
        for (int j = 0; j < 4; ++j)
            bf[j] = *(const s16x8*)&ldsB[(wn * 64 + j * 16 + r16) * 32 + quad * 8];
#pragma unroll
        for (int i = 0; i < 4; ++i)
#pragma unroll
            for (int j = 0; j < 4; ++j)
                acc[i][j] = __builtin_amdgcn_mfma_f32_16x16x32_bf16(af[i], bf[j], acc[i][j], 0, 0, 0);
        __syncthreads();
        ci0 += 32;
        if (ci0 == Cin) {
            ci0 = 0; ++tslot;
            if (TR) {
                unsigned e = (unsigned)(pack >> (tslot * 16)) & 0xFFFFu;
                dy = (int)((e >> 8) & 3) - 1; dx = (int)((e >> 4) & 3) - 1; wk = (int)(e & 15u);
            } else { ++wk; ++dx; if (dx == KW - pad) { dx = -pad; ++dy; } }
        }
    }

#pragma unroll
    for (int j = 0; j < 4; ++j) {
        int col = wn * 64 + j * 16 + r16; int ng = n0 + col;
        float bv = bias[ng];
#pragma unroll
        for (int i = 0; i < 4; ++i) {
            int mb = wm * 64 + i * 16 + quad * 4;
#pragma unroll
            for (int r = 0; r < 4; ++r) {
                int pos2 = blockM * BM + mb + r;
                long oaddr;
                if (TR) {
                    int ow2 = pos2 & Wm1; int t = pos2 >> lw;
                    int oh2 = t & Hm1;    int nb = t >> lh;
                    int oh = 2 * oh2 + py, ow = 2 * ow2 + px;
                    oaddr = ((long)(((nb << (lh + 1)) + oh) << (lw + 1)) + ow) * N + ng;
                } else {
                    oaddr = (long)pos2 * N + ng;
                }
                float v = acc[i][j][r] + bv;
                if (RELU) v = fmaxf(v, 0.f);
                if (OUTF32) {
                    ((float*)outv)[oaddr] = v;
                    if (DUALB) outb[oaddr] = f2bf(v);
                } else {
                    ((bfraw*)outv)[oaddr] = f2bf(v);
                }
            }
        }
    }
}

// ---------------------------------------------------------------------------
// dec2: convT k3 s1 p1, 64->3ch, fp32 NCHW out.
// Block = 16x16 output tile (grid 16 n * 256 tiles = 4096). Thread = 1 px.
// Full-channel staging: 18x18 halo x 64ch = 41,472 B LDS, single buffer, ONE
// barrier. Each 128B pixel record fetched exactly once (rows contiguous).
// 128B record == 32 banks -> sub-slot XOR swizzle by (px&7) on BOTH sides.
// OOB halo -> zero page. Weights: uniform -> scalar loads.
// ---------------------------------------------------------------------------
__global__ __launch_bounds__(256) void dec2_kernel(
    const bfraw* __restrict__ in, const float* __restrict__ wt,
    const float* __restrict__ bias, float* __restrict__ out,
    const bfraw* __restrict__ zp) {
    __shared__ __align__(16) bfraw tile[18 * 18 * 64];   // 41,472 B
    const int tid = threadIdx.x;
    const int b = blockIdx.x;
    const int n = b >> 8, t8 = b & 255;
    const int r0 = (t8 >> 4) * 16, c0 = (t8 & 15) * 16;
    const int wv = tid >> 6;
    const long nbase = (long)n * 65536;                  // px index base of image

    // ---- stage: 2592 segs of 16B (10 full passes + 32 tail) ----
#pragma unroll
    for (int k = 0; k < 10; ++k) {
        int t = k * 256 + tid;
        int px = t >> 3, d = t & 7;
        int pr = px / 18, pc = px - pr * 18;
        int ih = r0 - 1 + pr, iw = c0 - 1 + pc;
        bool ok = ((unsigned)ih < 256u) & ((unsigned)iw < 256u);
        int s = d ^ (px & 7);                            // pre-swizzled source sub-seg
        const bfraw* g = ok ? in + ((nbase + (long)ih * 256 + iw) << 6) + s * 8 : zp;
        gl_lds16(g, &tile[(k * 256 + wv * 64) * 8]);
    }
    if (tid < 32) {
        int t = 2560 + tid;
        int px = t >> 3, d = t & 7;
        int pr = px / 18, pc = px - pr * 18;
        int ih = r0 - 1 + pr, iw = c0 - 1 + pc;
        bool ok = ((unsigned)ih < 256u) & ((unsigned)iw < 256u);
        int s = d ^ (px & 7);
        const bfraw* g = ok ? in + ((nbase + (long)ih * 256 + iw) << 6) + s * 8 : zp;
        gl_lds16(g, &tile[2560 * 8]);
    }
    __syncthreads();

    // ---- compute: 1 output px per thread ----
    const int pr_out = tid >> 4, pc_out = tid & 15;
    float a0 = bias[0], a1 = bias[1], a2 = bias[2];
#pragma unroll
    for (int kh = 0; kh < 3; ++kh) {
#pragma unroll
        for (int kw = 0; kw < 3; ++kw) {
            const int q = (pr_out + 2 - kh) * 18 + (pc_out + 2 - kw);
            const int q7 = q & 7;
            const float* w0 = wt + (kh * 3 + kw) * 192;
#pragma unroll
            for (int j = 0; j < 8; ++j) {               // channel block j (ch 8j..8j+7)
                uint4 u = *(const uint4*)&tile[(q * 8 + (j ^ q7)) * 8];
                const float* wd = w0 + j * 24;
                float v0 = bflo(u.x), v1 = bfhi(u.x);
                float v2 = bflo(u.y), v3 = bfhi(u.y);
                float v4 = bflo(u.z), v5 = bfhi(u.z);
                float v6 = bflo(u.w), v7 = bfhi(u.w);
                a0 = fmaf(v0, wd[0],  a0); a1 = fmaf(v0, wd[1],  a1); a2 = fmaf(v0, wd[2],  a2);
                a0 = fmaf(v1, wd[3],  a0); a1 = fmaf(v1, wd[4],  a1); a2 = fmaf(v1, wd[5],  a2);
                a0 = fmaf(v2, wd[6],  a0); a1 = fmaf(v2, wd[7],  a1); a2 = fmaf(v2, wd[8],  a2);
                a0 = fmaf(v3, wd[9],  a0); a1 = fmaf(v3, wd[10], a1); a2 = fmaf(v3, wd[11], a2);
                a0 = fmaf(v4, wd[12], a0); a1 = fmaf(v4, wd[13], a1); a2 = fmaf(v4, wd[14], a2);
                a0 = fmaf(v5, wd[15], a0); a1 = fmaf(v5, wd[16], a1); a2 = fmaf(v5, wd[17], a2);
                a0 = fmaf(v6, wd[18], a0); a1 = fmaf(v6, wd[19], a1); a2 = fmaf(v6, wd[20], a2);
                a0 = fmaf(v7, wd[21], a0); a1 = fmaf(v7, wd[22], a1); a2 = fmaf(v7, wd[23], a2);
            }
        }
    }

    const int oh = r0 + pr_out, ow = c0 + pc_out;
    const long sp = (long)n * 196608;
    const long hw = (long)oh * 256 + ow;
    out[sp + hw] = a0; out[sp + 65536 + hw] = a1; out[sp + 131072 + hw] = a2;
}

// ---------------------------------------------------------------------------
// VQ via MFMA: S = Zb[128 x 256] x EbT (codes as B rows), dist = ||e||^2 - 2S.
// R7 structure: A[128][256] staged once, B[128][256] per 128-code chunk,
// both XOR-swizzled (d16 ^= row&7, both-sides: pre-swizzled global source +
// swizzled LDS read; XOR stays within each 128B line so coalescing holds).
// Per chunk: 8 ksteps x 16 MFMA with NO barriers (A/B resident), then
// barrier -> issue B prefetch for chunk+1 -> argmin epilogue (VALU, hides
// load latency) -> barrier (vmcnt drain completes prefetch). 8 barriers
// total vs 64. Per-lane argmin in ascending code order (strict < keeps
// first index); single cross-lane reduce at the end; wn-half merge via LDS.
// ---------------------------------------------------------------------------
__global__ __launch_bounds__(256) void vqm_kernel(
    const bfraw* __restrict__ zeb, const bfraw* __restrict__ embB,
    const float* __restrict__ esq, const float* __restrict__ emb,
    float* __restrict__ zq, bfraw* __restrict__ zqb, int* __restrict__ hist)
{
    __shared__ __align__(16) bfraw ldsA[128 * 256];   // 64 KB, swizzled
    __shared__ __align__(16) bfraw ldsB[128 * 256];   // 64 KB, swizzled
    __shared__ float sEsq[512];
    __shared__ float sVal[2][128];
    __shared__ int   sKey[2][128];
    __shared__ int   sIdx[128];
    const int tid = threadIdx.x, lane = tid & 63, wv = tid >> 6;
    const int wm = wv >> 1, wn = wv & 1;
    const int quad = lane >> 4, r16 = lane & 15;
    const int posBase = blockIdx.x * 128;

    for (int i = tid; i < 512; i += 256) sEsq[i] = esq[i];

    // ---- stage A (once) + B chunk 0; swizzle: LDS slot d16 holds global
    //      sub-seg d16 ^ (row&7) -> compute reads slot (d16 ^ (row&7)).
#pragma unroll
    for (int k = 0; k < 16; ++k) {
        int t = k * 256 + tid;
        int row = t >> 5, d16 = t & 31;
        gl_lds16(zeb + (((long)(posBase + row)) << 8) + ((d16 ^ (row & 7)) << 3),
                 &ldsA[(k * 256 + wv * 64) * 8]);
    }
#pragma unroll
    for (int k = 0; k < 16; ++k) {
        int t = k * 256 + tid;
        int code = t >> 5, d16 = t & 31;
        gl_lds16(embB + (((long)code) << 8) + ((d16 ^ (code & 7)) << 3),
                 &ldsB[(k * 256 + wv * 64) * 8]);
    }
    __syncthreads();

    float bestv[16]; int bestk[16];
#pragma unroll
    for (int t = 0; t < 16; ++t) { bestv[t] = 1e30f; bestk[t] = 1 << 30; }

    int arow[4], brow[4];
#pragma unroll
    for (int i = 0; i < 4; ++i) arow[i] = wm * 64 + i * 16 + r16;
#pragma unroll
    for (int j = 0; j < 4; ++j) brow[j] = wn * 64 + j * 16 + r16;

    for (int chunk = 0; chunk < 4; ++chunk) {
        f32x4 acc[4][4];
#pragma unroll
        for (int i = 0; i < 4; ++i)
#pragma unroll
            for (int j = 0; j < 4; ++j) acc[i][j] = (f32x4)0.f;

#pragma unroll
        for (int ks = 0; ks < 8; ++ks) {
            s16x8 af[4], bf[4];
#pragma unroll
            for (int i = 0; i < 4; ++i)
                af[i] = *(const s16x8*)&ldsA[arow[i] * 256 + (((ks * 4 + quad) ^ (arow[i] & 7)) << 3)];
#pragma unroll
            for (int j = 0; j < 4; ++j)
                bf[j] = *(const s16x8*)&ldsB[brow[j] * 256 + (((ks * 4 + quad) ^ (brow[j] & 7)) << 3)];
#pragma unroll
            for (int i = 0; i < 4; ++i)
#pragma unroll
                for (int j = 0; j < 4; ++j)
                    acc[i][j] = __builtin_amdgcn_mfma_f32_16x16x32_bf16(af[i], bf[j], acc[i][j], 0, 0, 0);
        }
        __syncthreads();                    // all waves done reading ldsB
        if (chunk < 3) {                    // prefetch next B chunk (drained at loop-end barrier)
#pragma unroll
            for (int k = 0; k < 16; ++k) {
                int t = k * 256 + tid;
                int code = t >> 5, d16 = t & 31;
                gl_lds16(embB + (((long)((chunk + 1) * 128 + code)) << 8) + ((d16 ^ (code & 7)) << 3),
                         &ldsB[(k * 256 + wv * 64) * 8]);
            }
        }
        // epilogue: per-lane argmin update (codes ascending -> strict < keeps
        // first index on ties). Runs on VALU while prefetch is in flight.
#pragma unroll
        for (int i = 0; i < 4; ++i)
#pragma unroll
            for (int j = 0; j < 4; ++j) {
                int code = chunk * 128 + wn * 64 + j * 16 + r16;
                float es = sEsq[code];
#pragma unroll
                for (int r = 0; r < 4; ++r) {
                    float d = es - 2.f * acc[i][j][r];
                    int s = i * 4 + r;
                    if (d < bestv[s]) { bestv[s] = d; bestk[s] = code; }
                }
            }
        __syncthreads();                    // vmcnt drain: next B chunk ready
    }

    // single cross-lane reduce over the 16-lane r16 group (xor masks 1..8)
#pragma unroll
    for (int s = 0; s < 16; ++s) {
        float v = bestv[s]; int kk = bestk[s];
#pragma unroll
        for (int m = 1; m < 16; m <<= 1) {
            float ov = __shfl_xor(v, m, 64);
            int   ok = __shfl_xor(kk, m, 64);
            if (ov < v || (ov == v && ok < kk)) { v = ov; kk = ok; }
        }
        bestv[s] = v; bestk[s] = kk;
    }
    // publish per-wave partials (each wave covered half the codes for its rows)
    if (r16 == 0) {
#pragma unroll
        for (int i = 0; i < 4; ++i)
#pragma unroll
            for (int r = 0; r < 4; ++r) {
                int localRow = wm * 64 + i * 16 + quad * 4 + r;
                int s = i * 4 + r;
                sVal[wn][localRow] = bestv[s];
                sKey[wn][localRow] = bestk[s];
            }
    }
    __syncthreads();
    // merge halves: one thread per row, single sIdx write + single hist atomic
    if (tid < 128) {
        float v0 = sVal[0][tid]; int k0 = sKey[0][tid];
        float v1 = sVal[1][tid]; int k1 = sKey[1][tid];
        int kk = (v1 < v0 || (v1 == v0 && k1 < k0)) ? k1 : k0;
        sIdx[tid] = kk;
        atomicAdd(&hist[kk], 1);
    }
    __syncthreads();
    const float4* emb4 = (const float4*)emb;
    float4*  zq4  = (float4*)(zq + (long)posBase * 256);
    ushort4* zqb4 = (ushort4*)(zqb + (long)posBase * 256);
    for (int i2 = tid; i2 < 128 * 64; i2 += 256) {
        int p = i2 >> 6, c = i2 & 63;
        float4 vv = emb4[sIdx[p] * 64 + c];
        zq4[i2] = vv;
        ushort4 u; u.x = f2bf(vv.x); u.y = f2bf(vv.y); u.z = f2bf(vv.z); u.w = f2bf(vv.w);
        zqb4[i2] = u;
    }
}

// --- perplexity
__global__ void ppl_kernel(const int* __restrict__ hist, float* __restrict__ outp) {
    __shared__ float red[512];
    int t = threadIdx.x;
    float p = (float)hist[t] * (1.0f / 65536.0f);
    red[t] = p * logf(p + 1e-10f);
    __syncthreads();
    for (int s = 256; s; s >>= 1) { if (t < s) red[t] += red[t + s]; __syncthreads(); }
    if (t == 0) *outp = expf(-red[0]);
}

// host: pack convT parity-class tap table (4 entries x 16 bits)
static unsigned long long packFor(int py, int px) {
    unsigned long long pk = 0; int s = 0;
    for (int kh = 0; kh < 4; ++kh) {
        if (((py + 1 - kh) & 1) != 0) continue;
        int dy = (py + 1 - kh) / 2;
        for (int kw = 0; kw < 4; ++kw) {
            if (((px + 1 - kw) & 1) != 0) continue;
            int dx = (px + 1 - kw) / 2;
            unsigned e = ((unsigned)(dy + 1) << 8) | ((unsigned)(dx + 1) << 4) | (unsigned)(kh * 4 + kw);
            pk |= (unsigned long long)e << (16 * s); ++s;
        }
    }
    return pk;
}

extern "C" void kernel_launch(void* const* d_in, const int* in_sizes, int n_in,
                              void* d_out, int out_size, void* d_ws, size_t ws_size,
                              hipStream_t stream) {
    const float* x       = (const float*)d_in[0];
    const float* w_enc1  = (const float*)d_in[1];
    const float* b_enc1  = (const float*)d_in[2];
    const float* w_enc2  = (const float*)d_in[3];
    const float* b_enc2  = (const float*)d_in[4];
    const float* w_prevq = (const float*)d_in[5];
    const float* b_prevq = (const float*)d_in[6];
    const float* emb     = (const float*)d_in[7];
    const float* w_post  = (const float*)d_in[8];
    const float* b_post  = (const float*)d_in[9];
    const float* w_dec1  = (const float*)d_in[10];
    const float* b_dec1  = (const float*)d_in[11];
    const float* w_dec2  = (const float*)d_in[12];
    const float* b_dec2  = (const float*)d_in[13];

    float* out = (float*)d_out;
    float* xr  = out;                     // 3,145,728
    float* ze  = out + 3145728;           // 16,777,216
    float* zq  = ze + 16777216;           // 16,777,216
    float* ppl = zq + 16777216;           // 1

    // ---- workspace carve (bytes) ----
    char* W = (char*)d_ws;
    float* wd2t = (float*)(W + 16384);      // dec2 fp32 [tap][ci][co]    7 KB
    float* esq  = (float*)(W + 24576);      // 2 KB
    int*   hist = (int*)(W + 28672);        // 2 KB
    bfraw* zp   = (bfraw*)(W + 32768);      // zero page, 256 B
    bfraw* w2b  = (bfraw*)(W + 560128);     // enc2  bf16 [co][16][64]   256 KB
    bfraw* w3b  = (bfraw*)(W + 822272);     // prevq bf16 [co][9][128]   576 KB
    bfraw* wpb  = (bfraw*)(W + 1412096);    // post  bf16 [co][16][256]  1 MB
    bfraw* wd1b = (bfraw*)(W + 2460672);    // dec1  bf16 [co][16][128]  256 KB
    bfraw* wb1  = (bfraw*)(W + 2722816);    // enc1  bf16 [co][64]        8 KB
    bfraw* embB = (bfraw*)(W + 2736128);    // emb   bf16 [512][256]    256 KB
    // bufX (128 MiB @ +4 MiB): sequential lifetimes
    //   a0 [0,33.5M) -> h2 [0,16.8M) -> zeb [16.8M,50.3M) -> zqb [50.3M,83.9M)
    //   -> ddec1 [0,134.2M)
    char* bufX = W + 4194304;
    bfraw* a0    = (bfraw*)bufX;
    bfraw* h2    = (bfraw*)bufX;
    bfraw* zeb   = (bfraw*)(bufX + 16777216);
    bfraw* zqb   = (bfraw*)(bufX + 50331648);
    bfraw* ddec1 = (bfraw*)bufX;
    // bufY (67.1 MB): dpost
    bfraw* dpost = (bfraw*)(W + 138412032);
    bfraw* h1    = (bfraw*)ze;              // alias: h1 dies before prevq writes z_e

    // ---- weight transforms + precomputes ----
    wt_kernel<<<8, 256, 0, stream>>>(w_dec2, wd2t, 3, 64, 3, 3, 1);
    wb1_kernel<<<16, 256, 0, stream>>>(w_enc1, wb1);
    wtb_kernel<<<512, 256, 0, stream>>>(w_enc2, w2b, 128, 64, 4, 4, 0);
    wtb_kernel<<<1152, 256, 0, stream>>>(w_prevq, w3b, 256, 128, 3, 3, 0);
    wtb_kernel<<<2048, 256, 0, stream>>>(w_post, wpb, 128, 256, 4, 4, 1);
    wtb_kernel<<<512, 256, 0, stream>>>(w_dec1, wd1b, 64, 128, 4, 4, 1);
    wtb_kernel<<<512, 256, 0, stream>>>(emb, embB, 512, 256, 1, 1, 0);
    embsq_kernel<<<512, 64, 0, stream>>>(emb, esq);
    hipMemsetAsync(hist, 0, 512 * sizeof(int), stream);
    hipMemsetAsync(zp, 0, 256, stream);

    // ---- encoder ----
    xpack_kernel<<<1024, 256, 0, stream>>>(x, a0);
    igemm_kernel<256, 64, 4, 1, false, true, false, false><<<dim3(1024, 1), 256, 0, stream>>>(
        a0, wb1, b_enc1, h1, nullptr, zp, 512, 512, 64, 1, 1, 2, 9, 9, 64, 1, 0, 0, 0, 0ULL);
    igemm_kernel<128, 128, 2, 2, false, true, false, false><<<dim3(512, 1), 256, 0, stream>>>(
        h1, w2b, b_enc2, h2, nullptr, zp, 128, 128, 64, 2, 16, 32, 6, 6, 128, 4, 1, 0, 0, 0ULL);
    // prevq: dual output ze fp32 + zeb bf16
    igemm_kernel<128, 128, 2, 2, false, false, true, true><<<dim3(512, 2), 256, 0, stream>>>(
        h2, w3b, b_prevq, ze, zeb, zp, 64, 64, 128, 1, 9, 36, 6, 6, 256, 3, 1, 0, 0, 0ULL);

    // ---- VQ (MFMA) ----
    vqm_kernel<<<512, 256, 0, stream>>>(zeb, embB, esq, emb, zq, zqb, hist);
    ppl_kernel<<<1, 512, 0, stream>>>(hist, ppl);

    // ---- decoder ----
    for (int cls = 0; cls < 4; ++cls) {
        int py = cls >> 1, px = cls & 1;
        igemm_kernel<128, 128, 2, 2, true, false, false, false><<<dim3(512, 1), 256, 0, stream>>>(
            zqb, wpb, b_post, dpost, nullptr, zp, 64, 64, 256, 1, 16, 32, 6, 6, 128, 4, 1,
            py, px, packFor(py, px));
    }
    for (int cls = 0; cls < 4; ++cls) {
        int py = cls >> 1, px = cls & 1;
        igemm_kernel<256, 64, 4, 1, true, true, false, false><<<dim3(1024, 1), 256, 0, stream>>>(
            dpost, wd1b, b_dec1, ddec1, nullptr, zp, 128, 128, 128, 1, 16, 16, 7, 7, 64, 4, 1,
            py, px, packFor(py, px));
    }
    dec2_kernel<<<4096, 256, 0, stream>>>(ddec1, wd2t, b_dec2, xr, zp);
}